// Round 16
// baseline (930.521 us; speedup 1.0000x reference)
//
#include <hip/hip_runtime.h>
#include <math.h>

#define NN 10000
#define NE 160000
#define NG 64
#define FEAT 80
#define NT 5
#define NL 4

// ---------------- setup kernels ----------------
__global__ void k_cnt2(const int* __restrict__ dst, const int* __restrict__ batch,
                       int* __restrict__ deg, int* __restrict__ gcnt) {
    int e = blockIdx.x * 256 + threadIdx.x;
    if (e < NE) atomicAdd(&deg[dst[e]], 1);
    if (e < NN) atomicAdd(&gcnt[batch[e]], 1);
}

__global__ void k_scan(const int* __restrict__ deg, int* __restrict__ offs) {
    __shared__ int sums[256];
    int tid = threadIdx.x;
    int start = tid * 40, stop = min(start + 40, NN);
    int s = 0;
    for (int i = start; i < stop; ++i) s += deg[i];
    sums[tid] = s;
    __syncthreads();
    for (int off = 1; off < 256; off <<= 1) {
        int v = (tid >= off) ? sums[tid - off] : 0;
        __syncthreads();
        sums[tid] += v;
        __syncthreads();
    }
    int base = (tid == 0) ? 0 : sums[tid - 1];
    for (int i = start; i < stop; ++i) { offs[i] = base; base += deg[i]; }
    if (tid == 255) offs[NN] = sums[255];
}

__global__ void k_ald(const int* __restrict__ deg, float* __restrict__ ald) {
    __shared__ float red[256];
    int i = blockIdx.x * 256 + threadIdx.x;
    red[threadIdx.x] = (i < NN) ? logf((float)deg[i] + 1.0f) : 0.0f;
    __syncthreads();
    for (int s = 128; s > 0; s >>= 1) {
        if (threadIdx.x < s) red[threadIdx.x] += red[threadIdx.x + s];
        __syncthreads();
    }
    if (threadIdx.x == 0) atomicAdd(ald, red[0]);
}

__global__ void k_fill(const int* __restrict__ src, const int* __restrict__ dst,
                       const int* __restrict__ offs, int* __restrict__ cursor,
                       int* __restrict__ csr) {
    int e = blockIdx.x * 256 + threadIdx.x;
    if (e < NE) {
        int d = dst[e];
        int p = atomicAdd(&cursor[d], 1);
        csr[offs[d] + p] = src[e];
    }
}

// hT is feature-major: hT[f*NN + n]
__global__ void k_op0(const float* __restrict__ x, const float* __restrict__ plW,
                      const float* __restrict__ plb, float* __restrict__ hT) {
    int i = blockIdx.x * 256 + threadIdx.x;  // i = f*NN + n
    if (i < FEAT * NN) {
        int f = i / NN, n = i - f * NN;
        hT[i] = x[2 * n] * plW[f] + plb[f];
    }
}

// ---------------- per-layer kernels ----------------
// A[n][c] (c = t*80+o, c<400) = sum_f h[n][f] * preW[t][f][o]        (dst half)
// Bt[t][n][o]                 = sum_f h[n][f] * preW[t][80+f][o]     (src half)
__global__ __launch_bounds__(256) void k_mm_ab(
        const float* __restrict__ hT, const float* __restrict__ preW_l,
        float* __restrict__ A, float* __restrict__ Bt) {
    __shared__ float hs[16][80];
    int n0 = blockIdx.x * 16;
    int tid = threadIdx.x;
    for (int i = tid; i < 16 * 80; i += 256) {
        int nl = i & 15, f = i >> 4;
        hs[nl][f] = hT[(size_t)f * NN + n0 + nl];
    }
    __syncthreads();
    int c0 = blockIdx.y * 512 + tid;  // slot0: c0, slot1: c0+256; combined c in [0,800)
    float acc[2][16];
#pragma unroll
    for (int s = 0; s < 2; s++)
#pragma unroll
        for (int i = 0; i < 16; i++) acc[s][i] = 0.f;
    const float* wp[2];
#pragma unroll
    for (int s = 0; s < 2; s++) {
        int c = c0 + s * 256;
        int part = (c >= 400) ? 1 : 0;
        int cc = c - part * 400;
        int t = cc / 80, o = cc - t * 80;
        wp[s] = preW_l + (size_t)(t * 160 + part * 80) * 80 + o;  // + f*80 per f
    }
    bool act1 = (c0 + 256) < 800;
    for (int fq = 0; fq < 80; fq += 4) {
        float w0a = wp[0][(fq + 0) * 80], w0b = wp[0][(fq + 1) * 80];
        float w0c = wp[0][(fq + 2) * 80], w0d = wp[0][(fq + 3) * 80];
        float w1a = 0.f, w1b = 0.f, w1c = 0.f, w1d = 0.f;
        if (act1) {
            w1a = wp[1][(fq + 0) * 80]; w1b = wp[1][(fq + 1) * 80];
            w1c = wp[1][(fq + 2) * 80]; w1d = wp[1][(fq + 3) * 80];
        }
#pragma unroll
        for (int i = 0; i < 16; i++) {
            float4 hv = *(const float4*)&hs[i][fq];
            acc[0][i] += hv.x * w0a + hv.y * w0b + hv.z * w0c + hv.w * w0d;
            acc[1][i] += hv.x * w1a + hv.y * w1b + hv.z * w1c + hv.w * w1d;
        }
    }
#pragma unroll
    for (int s = 0; s < 2; s++) {
        int c = c0 + s * 256;
        if (c < 800) {
            int part = (c >= 400) ? 1 : 0;
            int cc = c - part * 400;
            int t = cc / 80, o = cc - t * 80;
            if (part == 0) {
#pragma unroll
                for (int i = 0; i < 16; i++) A[(size_t)(n0 + i) * 400 + cc] = acc[s][i];
            } else {
#pragma unroll
                for (int i = 0; i < 16; i++)
                    Bt[((size_t)t * NN + n0 + i) * 80 + o] = acc[s][i];
            }
        }
    }
}

// Aggregation with transposed output. Block: 16 nodes x one t (grid 625 x 5).
// thread = (ni = tid>>4, cl = tid&15); lane-group gathers 5 c-strided values/edge.
// 4-edge unrolled gather loop -> ~20 outstanding loads per group (latency hiding).
// Output aggT[(t*320 + j)*NN + n], j = stat*80 + o, stats [mean|min|max|std].
__global__ __launch_bounds__(256) void k_agg_t(
        const float* __restrict__ A, const float* __restrict__ Bt,
        const int* __restrict__ offs, const int* __restrict__ csr,
        const float* __restrict__ preb_l, float* __restrict__ aggT) {
    __shared__ float st[320 * 17];
    int tid = threadIdx.x;
    int t = blockIdx.y;
    int n0 = blockIdx.x * 16;
    int ni = tid >> 4;   // node within block
    int cl = tid & 15;   // c-lane
    int n = n0 + ni;     // NN = 625*16 exact, no guard
    int e0 = offs[n], e1 = offs[n + 1];
    const float* Bts = Bt + (size_t)t * NN * 80;
    float s[5], q[5], mn[5], mx[5];
#pragma unroll
    for (int k = 0; k < 5; k++) { s[k] = 0.f; q[k] = 0.f; mn[k] = 3.4e38f; mx[k] = -3.4e38f; }
    int e = e0;
    for (; e + 3 < e1; e += 4) {
        const float* br0 = Bts + (size_t)csr[e] * 80 + cl;
        const float* br1 = Bts + (size_t)csr[e + 1] * 80 + cl;
        const float* br2 = Bts + (size_t)csr[e + 2] * 80 + cl;
        const float* br3 = Bts + (size_t)csr[e + 3] * 80 + cl;
#pragma unroll
        for (int k = 0; k < 5; k++) {
            float b0 = br0[k * 16];
            float b1 = br1[k * 16];
            float b2 = br2[k * 16];
            float b3 = br3[k * 16];
            s[k] += (b0 + b1) + (b2 + b3);
            q[k] += (b0 * b0 + b1 * b1) + (b2 * b2 + b3 * b3);
            mn[k] = fminf(mn[k], fminf(fminf(b0, b1), fminf(b2, b3)));
            mx[k] = fmaxf(mx[k], fmaxf(fmaxf(b0, b1), fmaxf(b2, b3)));
        }
    }
    for (; e < e1; ++e) {
        const float* br = Bts + (size_t)csr[e] * 80 + cl;
#pragma unroll
        for (int k = 0; k < 5; k++) {
            float b = br[k * 16];
            s[k] += b; q[k] += b * b;
            mn[k] = fminf(mn[k], b); mx[k] = fmaxf(mx[k], b);
        }
    }
    int d = e1 - e0;
    float degf = (float)d;
    float cnt = fmaxf(degf, 1.f);
#pragma unroll
    for (int k = 0; k < 5; k++) {
        int c = cl + k * 16;
        float a = A[(size_t)n * 400 + t * 80 + c] + preb_l[t * 80 + c];
        float mean = (degf * a + s[k]) / cnt;
        float msq  = (degf * a * a + 2.f * a * s[k] + q[k]) / cnt;
        float sd = sqrtf(fmaxf(msq - mean * mean, 0.f) + 1e-5f);
        float mnr = (d > 0) ? a + mn[k] : 0.f;
        float mxr = (d > 0) ? a + mx[k] : 0.f;
        st[(0 * 80 + c) * 17 + ni] = mean;
        st[(1 * 80 + c) * 17 + ni] = mnr;
        st[(2 * 80 + c) * 17 + ni] = mxr;
        st[(3 * 80 + c) * 17 + ni] = sd;
    }
    __syncthreads();
    int jj = tid >> 4;
    int nl = tid & 15;
#pragma unroll
    for (int pass = 0; pass < 20; ++pass) {
        int j = pass * 16 + jj;
        aggT[((size_t)t * 320 + j) * NN + n0 + nl] = st[j * 17 + nl];
    }
}

// Wh[f][fo] = sum_{t,o2} postW[t][f][o2] * linW[t*16+o2][fo]  (h-part folded thru
// lin; exact math verified R7 at absmax 0). MUST run after k_agg_t (Wh lives in
// dead-Bt space).
__global__ void k_wh(const float* __restrict__ postW_l, const float* __restrict__ linW_l,
                     float* __restrict__ Wh) {
    int f = blockIdx.x;
    int fo = threadIdx.x;
    if (fo >= 80) return;
    float s = 0.f;
    for (int t = 0; t < NT; ++t) {
        const float* w0 = postW_l + ((size_t)t * 1040 + f) * 16;
#pragma unroll
        for (int o2 = 0; o2 < 16; ++o2)
            s += w0[o2] * linW_l[(t * 16 + o2) * 80 + fo];
    }
    Wh[f * 80 + fo] = s;
}

// k_post v9: tiled GEMM [256n x 320j] @ [320j x 48(3p x 16o)] per t.
// grid (40, 5, 4): z = jq (j-chunk of 80). 16-j sub-chunks staged in LDS via
// coalesced float4 loads; thread = (nl 0..63, oq 0..3) owns 4n x 4o x 3parts =
// 48 acc -> per j: 4 LDS b128 per 48 FMA (VALU-bound, vs v5's 12 b128/48 FMA).
// No h-part (folded into k_lin via Wh). postb at jq==0; jq-partials via fp32
// atomics into y0T (zeroed per layer).
__global__ __launch_bounds__(256) void k_post(
        const float* __restrict__ aggT, const float* __restrict__ postW_l,
        const float* __restrict__ postb_l, const int* __restrict__ offs,
        const float* __restrict__ ald_sum, float* __restrict__ y0T) {
    __shared__ float stile[16 * 256];     // 16 KB
    __shared__ float wjs[16 * 48];        // 3 KB
    __shared__ float c1s[256], c2s[256];  // 2 KB
    int tid = threadIdx.x;
    int nl = tid & 63;     // 0..63
    int oq = tid >> 6;     // 0..3
    int t = blockIdx.y;
    int jq = blockIdx.z;   // block-uniform -> scalar
    int n0 = blockIdx.x * 256;
    int j0 = jq * 80;
    const float* W1 = postW_l + (size_t)t * 1040 * 16 + 80 * 16;
    const float* W2 = W1 + 320 * 16;
    const float* W3 = W2 + 320 * 16;
    {
        int n = n0 + tid;
        float ald = ald_sum[0] * (1.f / NN);
        if (n < NN) {
            float degf = (float)(offs[n + 1] - offs[n]);
            float logd = logf(fmaxf(degf, 1.f) + 1.f);
            c1s[tid] = logd / ald;
            c2s[tid] = ald / logd;
        } else { c1s[tid] = 0.f; c2s[tid] = 0.f; }
    }
    float acc1[16], acc2[16], acc3[16];  // [ni*4+oi]
#pragma unroll
    for (int i = 0; i < 16; i++) { acc1[i] = 0.f; acc2[i] = 0.f; acc3[i] = 0.f; }
    bool full = (n0 + 256 <= NN);
    for (int jc = 0; jc < 80; jc += 16) {
        __syncthreads();
        // stage stile[16 j][256 n]: 1024 float4 / 256 threads
#pragma unroll
        for (int k = 0; k < 4; ++k) {
            int idx = k * 256 + tid;
            int j = idx >> 6;
            int n4 = (idx & 63) * 4;
            const float* rowp = aggT + ((size_t)(t * 320 + j0 + jc + j)) * NN + n0;
            float4 v;
            if (full) {
                v = *(const float4*)(rowp + n4);
            } else {
                v.x = (n0 + n4     < NN) ? rowp[n4]     : 0.f;
                v.y = (n0 + n4 + 1 < NN) ? rowp[n4 + 1] : 0.f;
                v.z = (n0 + n4 + 2 < NN) ? rowp[n4 + 2] : 0.f;
                v.w = (n0 + n4 + 3 < NN) ? rowp[n4 + 3] : 0.f;
            }
            *(float4*)(stile + j * 256 + n4) = v;
        }
        // stage wjs[16 j][48]: 768 / 256 threads
#pragma unroll
        for (int k = 0; k < 3; ++k) {
            int idx = k * 256 + tid;
            int j = idx / 48;
            int rem = idx - j * 48;
            int pp = rem >> 4, o = rem & 15;
            const float* Wp = (pp == 0) ? W1 : (pp == 1) ? W2 : W3;
            wjs[idx] = Wp[(j0 + jc + j) * 16 + o];
        }
        __syncthreads();
#pragma unroll 4
        for (int j = 0; j < 16; ++j) {
            float4 sv = *(const float4*)(stile + j * 256 + nl * 4);
            const float* w = wjs + j * 48 + oq * 4;
            float4 w1 = *(const float4*)(w);
            float4 w2 = *(const float4*)(w + 16);
            float4 w3 = *(const float4*)(w + 32);
            float sa[4] = {sv.x, sv.y, sv.z, sv.w};
            float wa1[4] = {w1.x, w1.y, w1.z, w1.w};
            float wa2[4] = {w2.x, w2.y, w2.z, w2.w};
            float wa3[4] = {w3.x, w3.y, w3.z, w3.w};
#pragma unroll
            for (int ni = 0; ni < 4; ++ni)
#pragma unroll
                for (int oi = 0; oi < 4; ++oi) {
                    acc1[ni * 4 + oi] += sa[ni] * wa1[oi];
                    acc2[ni * 4 + oi] += sa[ni] * wa2[oi];
                    acc3[ni * 4 + oi] += sa[ni] * wa3[oi];
                }
        }
    }
#pragma unroll
    for (int ni = 0; ni < 4; ++ni) {
        int nn = n0 + nl * 4 + ni;
        if (nn < NN) {
            float c1 = c1s[nl * 4 + ni], c2 = c2s[nl * 4 + ni];
#pragma unroll
            for (int oi = 0; oi < 4; ++oi) {
                int o = oq * 4 + oi;
                float v = acc1[ni * 4 + oi] + c1 * acc2[ni * 4 + oi] + c2 * acc3[ni * 4 + oi];
                if (jq == 0) v += postb_l[t * 16 + o];
                unsafeAtomicAdd(&y0T[(size_t)(t * 16 + o) * NN + nn], v);
            }
        }
    }
}

// k_lin v5: grid (40, 10), 8 f per block, both weight tiles LDS-staged.
// yT[f][n] = sum_k y0T[k][n]*linW[k][f] + sum_f' hT[f'][n]*Wh[f'][f] + linb[f]
__global__ __launch_bounds__(256) void k_lin(
        const float* __restrict__ y0T, const float* __restrict__ hT,
        const float* __restrict__ linW_l, const float* __restrict__ Wh,
        const float* __restrict__ linb_l, float* __restrict__ yT) {
    __shared__ float ws[80 * 8];   // 2.56 KB
    __shared__ float whs[80 * 8];  // 2.56 KB
    int tid = threadIdx.x;
    int f0 = blockIdx.y * 8;
    for (int idx = tid; idx < 80 * 8; idx += 256) {
        ws[idx]  = linW_l[(idx >> 3) * 80 + f0 + (idx & 7)];
        whs[idx] = Wh[(idx >> 3) * 80 + f0 + (idx & 7)];
    }
    __syncthreads();
    int n = blockIdx.x * 256 + tid;
    bool alive = (n < NN);
    int nc = alive ? n : 0;
    float acc[8];
#pragma unroll
    for (int i = 0; i < 8; i++) acc[i] = 0.f;
#pragma unroll 8
    for (int k = 0; k < 80; ++k) {
        float v = y0T[(size_t)k * NN + nc];
        const float4 wa = *(const float4*)(ws + k * 8);
        const float4 wb = *(const float4*)(ws + k * 8 + 4);
        acc[0] += v * wa.x; acc[1] += v * wa.y; acc[2] += v * wa.z; acc[3] += v * wa.w;
        acc[4] += v * wb.x; acc[5] += v * wb.y; acc[6] += v * wb.z; acc[7] += v * wb.w;
    }
#pragma unroll 8
    for (int k = 0; k < 80; ++k) {
        float v = hT[(size_t)k * NN + nc];
        const float4 wa = *(const float4*)(whs + k * 8);
        const float4 wb = *(const float4*)(whs + k * 8 + 4);
        acc[0] += v * wa.x; acc[1] += v * wa.y; acc[2] += v * wa.z; acc[3] += v * wa.w;
        acc[4] += v * wb.x; acc[5] += v * wb.y; acc[6] += v * wb.z; acc[7] += v * wb.w;
    }
    if (alive) {
#pragma unroll
        for (int i = 0; i < 8; i++)
            yT[(size_t)(f0 + i) * NN + n] = acc[i] + linb_l[f0 + i];
    }
}

// k_bnstats v2: grid (80, 8). Each block reduces a 1250-node segment of one f;
// 2 fp32 atomics into launch-zeroed bnst.
__global__ void k_bnstats(const float* __restrict__ yT, float* __restrict__ bnst) {
    __shared__ float r1[256], r2[256];
    int f = blockIdx.x;
    int seg = blockIdx.y;
    int tid = threadIdx.x;
    int i0 = seg * 1250, i1 = min(i0 + 1250, NN);
    float s = 0.f, q = 0.f;
    for (int i = i0 + tid; i < i1; i += 256) {
        float v = yT[(size_t)f * NN + i];
        s += v; q += v * v;
    }
    r1[tid] = s; r2[tid] = q;
    __syncthreads();
    for (int st = 128; st > 0; st >>= 1) {
        if (tid < st) { r1[tid] += r1[tid + st]; r2[tid] += r2[tid + st]; }
        __syncthreads();
    }
    if (tid == 0) {
        unsafeAtomicAdd(&bnst[f], r1[0]);
        unsafeAtomicAdd(&bnst[80 + f], r2[0]);
    }
}

__global__ void k_bn(const float* __restrict__ yT, const float* __restrict__ bnst,
                     const float* __restrict__ gamma_l, const float* __restrict__ beta_l,
                     float* __restrict__ hT) {
    int i = blockIdx.x * 256 + threadIdx.x;
    if (i >= FEAT * NN) return;
    int f = i / NN;
    float mu = bnst[f] * (1.f / NN);
    float msq = bnst[80 + f] * (1.f / NN);
    float var = fmaxf(msq - mu * mu, 0.f);
    float v = (yT[i] - mu) * (1.f / sqrtf(var + 1e-5f)) * gamma_l[f] + beta_l[f];
    hT[i] = fmaxf(v, 0.f);
}

// Last layer: fused bn + relu + xc + log. Thread handles (f, n) with f in
// [0,40); computes bn for f and f+40, writes lxc directly (hT is dead).
__global__ void k_bnxc(const float* __restrict__ yT, const float* __restrict__ bnst,
                       const float* __restrict__ gamma_l, const float* __restrict__ beta_l,
                       const float* __restrict__ x, float* __restrict__ lxc) {
    int i = blockIdx.x * 256 + threadIdx.x;  // i = f*NN + n, f in [0,40)
    if (i >= 40 * NN) return;
    int f = i / NN, n = i - f * NN;
    int f2 = f + 40;
    float mu1 = bnst[f] * (1.f / NN);
    float ms1 = bnst[80 + f] * (1.f / NN);
    float v1 = (yT[(size_t)f * NN + n] - mu1) *
               (1.f / sqrtf(fmaxf(ms1 - mu1 * mu1, 0.f) + 1e-5f)) * gamma_l[f] + beta_l[f];
    v1 = fmaxf(v1, 0.f);
    float mu2 = bnst[f2] * (1.f / NN);
    float ms2 = bnst[80 + f2] * (1.f / NN);
    float v2 = (yT[(size_t)f2 * NN + n] - mu2) *
               (1.f / sqrtf(fmaxf(ms2 - mu2 * mu2, 0.f) + 1e-5f)) * gamma_l[f2] + beta_l[f2];
    v2 = fmaxf(v2, 0.f);
    lxc[(size_t)n * 40 + f] = logf(v1 * x[2 * n + 1] + v2 + 1e-6f);
}

// ---------------- tail kernels ----------------
__global__ void k_logagg(const float* __restrict__ lxc, const int* __restrict__ offs,
                         const int* __restrict__ csr, const int* __restrict__ batch,
                         float* __restrict__ pooled) {
    int n = blockIdx.x;
    int tid = threadIdx.x;  // 64
    if (tid >= 40) return;
    int e0 = offs[n], e1 = offs[n + 1];
    float s = 0.f;
    for (int k = e0; k < e1; ++k) s += lxc[(size_t)csr[k] * 40 + tid];
    float v = expf(s + lxc[(size_t)n * 40 + tid]);
    atomicAdd(&pooled[batch[n] * 40 + tid], v);
}

__global__ void k_final(const float* __restrict__ pooled, const int* __restrict__ gcnt,
                        const float* __restrict__ mlW, const float* __restrict__ mlb,
                        const float* __restrict__ m1W, const float* __restrict__ m1b,
                        const float* __restrict__ m2W, const float* __restrict__ m2b,
                        float* __restrict__ out) {
    int g = threadIdx.x;
    if (g >= NG) return;
    float inv = 1.f / fmaxf((float)gcnt[g], 1.f);
    float pl[40];
#pragma unroll
    for (int j = 0; j < 40; j++) pl[j] = pooled[g * 40 + j] * inv;
    float xl = mlb[0];
#pragma unroll
    for (int j = 0; j < 40; j++) xl += pl[j] * mlW[j];
    float acc = m2b[0];
    for (int k = 0; k < 20; k++) {
        float v = m1b[k];
#pragma unroll
        for (int j = 0; j < 40; j++) v += pl[j] * m1W[j * 20 + k];
        v = 20.f - fmaxf(v, 0.f);
        acc += v * m2W[k];
    }
    out[g] = acc + xl;
}

// ---------------- launcher ----------------
extern "C" void kernel_launch(void* const* d_in, const int* in_sizes, int n_in,
                              void* d_out, int out_size, void* d_ws, size_t ws_size,
                              hipStream_t stream) {
    const float* x     = (const float*)d_in[0];
    const int*   ei    = (const int*)d_in[1];
    const int*   batch = (const int*)d_in[2];
    const float* plW   = (const float*)d_in[3];
    const float* plb   = (const float*)d_in[4];
    const float* preW  = (const float*)d_in[5];
    const float* preb  = (const float*)d_in[6];
    const float* postW = (const float*)d_in[7];
    const float* postb = (const float*)d_in[8];
    const float* linW  = (const float*)d_in[9];
    const float* linb  = (const float*)d_in[10];
    const float* bnG   = (const float*)d_in[11];
    const float* bnB   = (const float*)d_in[12];
    const float* mlW   = (const float*)d_in[13];
    const float* mlb   = (const float*)d_in[14];
    const float* m1W   = (const float*)d_in[15];
    const float* m1b   = (const float*)d_in[16];
    const float* m2W   = (const float*)d_in[17];
    const float* m2b   = (const float*)d_in[18];
    float* out = (float*)d_out;
    const int* srcp = ei;
    const int* dstp = ei + NE;

    char* p = (char*)d_ws;
    int*   deg    = (int*)(p + 0);          // 40000 B (zeroed)
    int*   cursor = (int*)(p + 40000);      // 40000 B (zeroed)
    int*   gcnt   = (int*)(p + 80000);      // 256 B   (zeroed)
    float* ald    = (float*)(p + 80256);    // 16 B    (zeroed)
    float* pooled = (float*)(p + 80272);    // 10240 B (zeroed)
    float* bnst   = (float*)(p + 90512);    // 2560 B  (zeroed; atomic-accumulated)
    int*   offs   = (int*)(p + 93072);      // 40016 B
    int*   csr    = (int*)(p + 133088);     // 640000 B
    float* hT     = (float*)(p + 773088);   // 3.2 MB  [80][NN]      (live across layers)
    float* A      = (float*)(p + 3973088);  // 16 MB   [NN][400]
    float* Bt     = (float*)(p + 19973088); // 16 MB   [5][NN][80]
    float* aggT   = (float*)(p + 35973088); // 64 MB   [5*320][NN]
    // Time-disjoint overlays inside the Bt region (Bt dead after k_agg_t):
    float* y0T = (float*)(p + 23173088);    // 3.2 MB  [80][NN]  (k_post atomic -> k_lin)
    float* yT  = (float*)(p + 26373088);    // 3.2 MB  [80][NN]  (k_lin -> bn)
    float* Wh  = (float*)(p + 29573088);    // 25.6 KB [80][80]  (k_wh -> k_lin; AFTER k_agg_t!)
    float* lxc = (float*)(p + 35973088);    // 1.6 MB  [NN][40]  (tail, overlays aggT)

    hipMemsetAsync(d_ws, 0, 93072, stream);
    k_cnt2<<<dim3((NE + 255) / 256), 256, 0, stream>>>(dstp, batch, deg, gcnt);
    k_scan<<<1, 256, 0, stream>>>(deg, offs);
    k_ald<<<dim3((NN + 255) / 256), 256, 0, stream>>>(deg, ald);
    k_fill<<<dim3((NE + 255) / 256), 256, 0, stream>>>(srcp, dstp, offs, cursor, csr);
    k_op0<<<dim3((FEAT * NN + 255) / 256), 256, 0, stream>>>(x, plW, plb, hT);

    for (int l = 0; l < NL; ++l) {
        const float* preW_l  = preW  + (size_t)l * NT * 160 * 80;
        const float* preb_l  = preb  + l * NT * 80;
        const float* postW_l = postW + (size_t)l * NT * 1040 * 16;
        const float* postb_l = postb + l * NT * 16;
        const float* linW_l  = linW  + l * 80 * 80;
        const float* linb_l  = linb  + l * 80;
        float* bnst_l = bnst + l * 160;
        k_mm_ab<<<dim3(625, 2), 256, 0, stream>>>(hT, preW_l, A, Bt);
        k_agg_t<<<dim3(625, 5), 256, 0, stream>>>(A, Bt, offs, csr, preb_l, aggT);
        // Bt dead from here; y0T/yT/Wh overlays safe
        hipMemsetAsync(y0T, 0, (size_t)80 * NN * 4, stream);
        k_wh<<<dim3(80), 128, 0, stream>>>(postW_l, linW_l, Wh);
        k_post<<<dim3(40, 5, 4), 256, 0, stream>>>(aggT, postW_l, postb_l, offs, ald, y0T);
        k_lin<<<dim3(40, 10), 256, 0, stream>>>(y0T, hT, linW_l, Wh, linb_l, yT);
        k_bnstats<<<dim3(80, 8), 256, 0, stream>>>(yT, bnst_l);
        if (l < NL - 1) {
            k_bn<<<dim3((FEAT * NN + 255) / 256), 256, 0, stream>>>(
                yT, bnst_l, bnG + l * 80, bnB + l * 80, hT);
        } else {
            k_bnxc<<<dim3((40 * NN + 255) / 256), 256, 0, stream>>>(
                yT, bnst_l, bnG + l * 80, bnB + l * 80, x, lxc);
        }
    }

    k_logagg<<<dim3(NN), 64, 0, stream>>>(lxc, offs, csr, batch, pooled);
    k_final<<<1, 64, 0, stream>>>(pooled, gcnt, mlW, mlb, m1W, m1b, m2W, m2b, out);
}

// Round 17
// 834.383 us; speedup vs baseline: 1.1152x; 1.1152x over previous
//
#include <hip/hip_runtime.h>
#include <math.h>

#define NN 10000
#define NE 160000
#define NG 64
#define FEAT 80
#define NT 5
#define NL 4

// ---------------- setup kernels ----------------
__global__ void k_cnt2(const int* __restrict__ dst, const int* __restrict__ batch,
                       int* __restrict__ deg, int* __restrict__ gcnt) {
    int e = blockIdx.x * 256 + threadIdx.x;
    if (e < NE) atomicAdd(&deg[dst[e]], 1);
    if (e < NN) atomicAdd(&gcnt[batch[e]], 1);
}

__global__ void k_scan(const int* __restrict__ deg, int* __restrict__ offs) {
    __shared__ int sums[256];
    int tid = threadIdx.x;
    int start = tid * 40, stop = min(start + 40, NN);
    int s = 0;
    for (int i = start; i < stop; ++i) s += deg[i];
    sums[tid] = s;
    __syncthreads();
    for (int off = 1; off < 256; off <<= 1) {
        int v = (tid >= off) ? sums[tid - off] : 0;
        __syncthreads();
        sums[tid] += v;
        __syncthreads();
    }
    int base = (tid == 0) ? 0 : sums[tid - 1];
    for (int i = start; i < stop; ++i) { offs[i] = base; base += deg[i]; }
    if (tid == 255) offs[NN] = sums[255];
}

__global__ void k_ald(const int* __restrict__ deg, float* __restrict__ ald) {
    __shared__ float red[256];
    int i = blockIdx.x * 256 + threadIdx.x;
    red[threadIdx.x] = (i < NN) ? logf((float)deg[i] + 1.0f) : 0.0f;
    __syncthreads();
    for (int s = 128; s > 0; s >>= 1) {
        if (threadIdx.x < s) red[threadIdx.x] += red[threadIdx.x + s];
        __syncthreads();
    }
    if (threadIdx.x == 0) atomicAdd(ald, red[0]);
}

__global__ void k_fill(const int* __restrict__ src, const int* __restrict__ dst,
                       const int* __restrict__ offs, int* __restrict__ cursor,
                       int* __restrict__ csr) {
    int e = blockIdx.x * 256 + threadIdx.x;
    if (e < NE) {
        int d = dst[e];
        int p = atomicAdd(&cursor[d], 1);
        csr[offs[d] + p] = src[e];
    }
}

// hT is feature-major: hT[f*NN + n]
__global__ void k_op0(const float* __restrict__ x, const float* __restrict__ plW,
                      const float* __restrict__ plb, float* __restrict__ hT) {
    int i = blockIdx.x * 256 + threadIdx.x;  // i = f*NN + n
    if (i < FEAT * NN) {
        int f = i / NN, n = i - f * NN;
        hT[i] = x[2 * n] * plW[f] + plb[f];
    }
}

// ---------------- per-layer kernels ----------------
// A[n][c] (c = t*80+o, c<400) = sum_f h[n][f] * preW[t][f][o]        (dst half)
// Bt[t][n][o]                 = sum_f h[n][f] * preW[t][80+f][o]     (src half)
__global__ __launch_bounds__(256) void k_mm_ab(
        const float* __restrict__ hT, const float* __restrict__ preW_l,
        float* __restrict__ A, float* __restrict__ Bt) {
    __shared__ float hs[16][80];
    int n0 = blockIdx.x * 16;
    int tid = threadIdx.x;
    for (int i = tid; i < 16 * 80; i += 256) {
        int nl = i & 15, f = i >> 4;
        hs[nl][f] = hT[(size_t)f * NN + n0 + nl];
    }
    __syncthreads();
    int c0 = blockIdx.y * 512 + tid;  // slot0: c0, slot1: c0+256; combined c in [0,800)
    float acc[2][16];
#pragma unroll
    for (int s = 0; s < 2; s++)
#pragma unroll
        for (int i = 0; i < 16; i++) acc[s][i] = 0.f;
    const float* wp[2];
#pragma unroll
    for (int s = 0; s < 2; s++) {
        int c = c0 + s * 256;
        int part = (c >= 400) ? 1 : 0;
        int cc = c - part * 400;
        int t = cc / 80, o = cc - t * 80;
        wp[s] = preW_l + (size_t)(t * 160 + part * 80) * 80 + o;  // + f*80 per f
    }
    bool act1 = (c0 + 256) < 800;
    for (int fq = 0; fq < 80; fq += 4) {
        float w0a = wp[0][(fq + 0) * 80], w0b = wp[0][(fq + 1) * 80];
        float w0c = wp[0][(fq + 2) * 80], w0d = wp[0][(fq + 3) * 80];
        float w1a = 0.f, w1b = 0.f, w1c = 0.f, w1d = 0.f;
        if (act1) {
            w1a = wp[1][(fq + 0) * 80]; w1b = wp[1][(fq + 1) * 80];
            w1c = wp[1][(fq + 2) * 80]; w1d = wp[1][(fq + 3) * 80];
        }
#pragma unroll
        for (int i = 0; i < 16; i++) {
            float4 hv = *(const float4*)&hs[i][fq];
            acc[0][i] += hv.x * w0a + hv.y * w0b + hv.z * w0c + hv.w * w0d;
            acc[1][i] += hv.x * w1a + hv.y * w1b + hv.z * w1c + hv.w * w1d;
        }
    }
#pragma unroll
    for (int s = 0; s < 2; s++) {
        int c = c0 + s * 256;
        if (c < 800) {
            int part = (c >= 400) ? 1 : 0;
            int cc = c - part * 400;
            int t = cc / 80, o = cc - t * 80;
            if (part == 0) {
#pragma unroll
                for (int i = 0; i < 16; i++) A[(size_t)(n0 + i) * 400 + cc] = acc[s][i];
            } else {
#pragma unroll
                for (int i = 0; i < 16; i++)
                    Bt[((size_t)t * NN + n0 + i) * 80 + o] = acc[s][i];
            }
        }
    }
}

// Aggregation with transposed output. Block: 16 nodes x one t (grid 625 x 5).
// thread = (ni = tid>>4, cl = tid&15); lane-group gathers 5 c-strided values/edge.
// 4-edge unrolled gather loop -> ~20 outstanding loads per group (latency hiding).
// Output aggT[(t*320 + j)*NN + n], j = stat*80 + o, stats [mean|min|max|std].
__global__ __launch_bounds__(256) void k_agg_t(
        const float* __restrict__ A, const float* __restrict__ Bt,
        const int* __restrict__ offs, const int* __restrict__ csr,
        const float* __restrict__ preb_l, float* __restrict__ aggT) {
    __shared__ float st[320 * 17];
    int tid = threadIdx.x;
    int t = blockIdx.y;
    int n0 = blockIdx.x * 16;
    int ni = tid >> 4;   // node within block
    int cl = tid & 15;   // c-lane
    int n = n0 + ni;     // NN = 625*16 exact, no guard
    int e0 = offs[n], e1 = offs[n + 1];
    const float* Bts = Bt + (size_t)t * NN * 80;
    float s[5], q[5], mn[5], mx[5];
#pragma unroll
    for (int k = 0; k < 5; k++) { s[k] = 0.f; q[k] = 0.f; mn[k] = 3.4e38f; mx[k] = -3.4e38f; }
    int e = e0;
    for (; e + 3 < e1; e += 4) {
        const float* br0 = Bts + (size_t)csr[e] * 80 + cl;
        const float* br1 = Bts + (size_t)csr[e + 1] * 80 + cl;
        const float* br2 = Bts + (size_t)csr[e + 2] * 80 + cl;
        const float* br3 = Bts + (size_t)csr[e + 3] * 80 + cl;
#pragma unroll
        for (int k = 0; k < 5; k++) {
            float b0 = br0[k * 16];
            float b1 = br1[k * 16];
            float b2 = br2[k * 16];
            float b3 = br3[k * 16];
            s[k] += (b0 + b1) + (b2 + b3);
            q[k] += (b0 * b0 + b1 * b1) + (b2 * b2 + b3 * b3);
            mn[k] = fminf(mn[k], fminf(fminf(b0, b1), fminf(b2, b3)));
            mx[k] = fmaxf(mx[k], fmaxf(fmaxf(b0, b1), fmaxf(b2, b3)));
        }
    }
    for (; e < e1; ++e) {
        const float* br = Bts + (size_t)csr[e] * 80 + cl;
#pragma unroll
        for (int k = 0; k < 5; k++) {
            float b = br[k * 16];
            s[k] += b; q[k] += b * b;
            mn[k] = fminf(mn[k], b); mx[k] = fmaxf(mx[k], b);
        }
    }
    int d = e1 - e0;
    float degf = (float)d;
    float cnt = fmaxf(degf, 1.f);
#pragma unroll
    for (int k = 0; k < 5; k++) {
        int c = cl + k * 16;
        float a = A[(size_t)n * 400 + t * 80 + c] + preb_l[t * 80 + c];
        float mean = (degf * a + s[k]) / cnt;
        float msq  = (degf * a * a + 2.f * a * s[k] + q[k]) / cnt;
        float sd = sqrtf(fmaxf(msq - mean * mean, 0.f) + 1e-5f);
        float mnr = (d > 0) ? a + mn[k] : 0.f;
        float mxr = (d > 0) ? a + mx[k] : 0.f;
        st[(0 * 80 + c) * 17 + ni] = mean;
        st[(1 * 80 + c) * 17 + ni] = mnr;
        st[(2 * 80 + c) * 17 + ni] = mxr;
        st[(3 * 80 + c) * 17 + ni] = sd;
    }
    __syncthreads();
    int jj = tid >> 4;
    int nl = tid & 15;
#pragma unroll
    for (int pass = 0; pass < 20; ++pass) {
        int j = pass * 16 + jj;
        aggT[((size_t)t * 320 + j) * NN + n0 + nl] = st[j * 17 + nl];
    }
}

// k_post v5 (R10/R15-proven): grid (40, 5, 4), z = jq (block-uniform). Each
// thread computes all 16 o for its n (48 acc chains); aggT read exactly once.
// Weights staged in LDS; c1/c2/postb in-thread; jq-partials via fp32 atomic
// add into y0T (zeroed per layer). NOTE: 1 n/thread keeps atomic stores
// lane-contiguous — R16's 4n tiling caused 4x HBM write amplification.
__global__ __launch_bounds__(256) void k_post(
        const float* __restrict__ hT, const float* __restrict__ aggT,
        const float* __restrict__ postW_l, const float* __restrict__ postb_l,
        const int* __restrict__ offs, const float* __restrict__ ald_sum,
        float* __restrict__ y0T) {
    __shared__ float wj[80 * 48];   // [jl][part(3)][o(16)]  15.36 KB
    __shared__ float wh[80 * 16];   // h-part weights (used when jq==0)  5.12 KB
    int tid = threadIdx.x;
    int t = blockIdx.y;
    int jq = blockIdx.z;   // block-uniform -> scalar
    int j0 = jq * 80;
    const float* W0 = postW_l + (size_t)t * 1040 * 16;
    const float* W1 = W0 + 80 * 16;
    const float* W2 = W0 + 400 * 16;
    const float* W3 = W0 + 720 * 16;
    // stage 80*48 weight floats: wj[j*48 + p*16 + o]
    for (int idx = tid; idx < 80 * 48; idx += 256) {
        int j = idx / 48;
        int rem = idx - j * 48;
        int p = rem >> 4, o = rem & 15;
        const float* Wp = (p == 0) ? W1 : (p == 1) ? W2 : W3;
        wj[idx] = Wp[(j0 + j) * 16 + o];
    }
    if (jq == 0) {
        for (int idx = tid; idx < 80 * 16; idx += 256)
            wh[idx] = W0[idx];
    }
    __syncthreads();
    int n = blockIdx.x * 256 + tid;
    bool alive = (n < NN);
    int nc = alive ? n : 0;
    float acc1[16], acc2[16], acc3[16];
#pragma unroll
    for (int i = 0; i < 16; i++) { acc1[i] = 0.f; acc2[i] = 0.f; acc3[i] = 0.f; }
    const float* ap = aggT + ((size_t)t * 320 + j0) * NN + nc;
#pragma unroll 8
    for (int j = 0; j < 80; ++j) {
        float a = ap[(size_t)j * NN];
        const float* w = wj + j * 48;
#pragma unroll
        for (int i = 0; i < 16; i++) {
            acc1[i] += a * w[i];
            acc2[i] += a * w[16 + i];
            acc3[i] += a * w[32 + i];
        }
    }
    if (jq == 0) {
#pragma unroll 4
        for (int f = 0; f < 80; ++f) {
            float hv = hT[(size_t)f * NN + nc];
            const float* w = wh + f * 16;
#pragma unroll
            for (int i = 0; i < 16; i++) acc1[i] += hv * w[i];
        }
    }
    if (alive) {
        float degf = (float)(offs[n + 1] - offs[n]);
        float ald = ald_sum[0] * (1.f / NN);
        float logd = logf(fmaxf(degf, 1.f) + 1.f);
        float c1 = logd / ald;
        float c2 = ald / logd;
#pragma unroll
        for (int i = 0; i < 16; i++) {
            float v = acc1[i] + c1 * acc2[i] + c2 * acc3[i];
            if (jq == 0) v += postb_l[t * 16 + i];
            unsafeAtomicAdd(&y0T[(size_t)(t * 16 + i) * NN + n], v);
        }
    }
}

// k_lin v2 (R8-proven): grid (40, 10), 8 f per block, weights LDS-staged.
// yT[f][n] = sum_k y0T[k][n] * linW[k][f] + linb[f]
__global__ __launch_bounds__(256) void k_lin(
        const float* __restrict__ y0T, const float* __restrict__ linW_l,
        const float* __restrict__ linb_l, float* __restrict__ yT) {
    __shared__ float ws[80 * 8];  // 2.56 KB
    int tid = threadIdx.x;
    int f0 = blockIdx.y * 8;
    for (int idx = tid; idx < 80 * 8; idx += 256)
        ws[idx] = linW_l[(idx >> 3) * 80 + f0 + (idx & 7)];
    __syncthreads();
    int n = blockIdx.x * 256 + tid;
    bool alive = (n < NN);
    int nc = alive ? n : 0;
    float acc[8];
#pragma unroll
    for (int i = 0; i < 8; i++) acc[i] = 0.f;
#pragma unroll 8
    for (int k = 0; k < 80; ++k) {
        float v = y0T[(size_t)k * NN + nc];
        const float4 wa = *(const float4*)(ws + k * 8);
        const float4 wb = *(const float4*)(ws + k * 8 + 4);
        acc[0] += v * wa.x; acc[1] += v * wa.y; acc[2] += v * wa.z; acc[3] += v * wa.w;
        acc[4] += v * wb.x; acc[5] += v * wb.y; acc[6] += v * wb.z; acc[7] += v * wb.w;
    }
    if (alive) {
#pragma unroll
        for (int i = 0; i < 8; i++)
            yT[(size_t)(f0 + i) * NN + n] = acc[i] + linb_l[f0 + i];
    }
}

// k_bnstats v2: grid (80, 8). Each block reduces a 1250-node segment of one f;
// 2 fp32 atomics into launch-zeroed bnst.
__global__ void k_bnstats(const float* __restrict__ yT, float* __restrict__ bnst) {
    __shared__ float r1[256], r2[256];
    int f = blockIdx.x;
    int seg = blockIdx.y;
    int tid = threadIdx.x;
    int i0 = seg * 1250, i1 = min(i0 + 1250, NN);
    float s = 0.f, q = 0.f;
    for (int i = i0 + tid; i < i1; i += 256) {
        float v = yT[(size_t)f * NN + i];
        s += v; q += v * v;
    }
    r1[tid] = s; r2[tid] = q;
    __syncthreads();
    for (int st = 128; st > 0; st >>= 1) {
        if (tid < st) { r1[tid] += r1[tid + st]; r2[tid] += r2[tid + st]; }
        __syncthreads();
    }
    if (tid == 0) {
        unsafeAtomicAdd(&bnst[f], r1[0]);
        unsafeAtomicAdd(&bnst[80 + f], r2[0]);
    }
}

__global__ void k_bn(const float* __restrict__ yT, const float* __restrict__ bnst,
                     const float* __restrict__ gamma_l, const float* __restrict__ beta_l,
                     float* __restrict__ hT) {
    int i = blockIdx.x * 256 + threadIdx.x;
    if (i >= FEAT * NN) return;
    int f = i / NN;
    float mu = bnst[f] * (1.f / NN);
    float msq = bnst[80 + f] * (1.f / NN);
    float var = fmaxf(msq - mu * mu, 0.f);
    float v = (yT[i] - mu) * (1.f / sqrtf(var + 1e-5f)) * gamma_l[f] + beta_l[f];
    hT[i] = fmaxf(v, 0.f);
}

// Last layer: fused bn + relu + xc + log. Thread handles (f, n) with f in
// [0,40); computes bn for f and f+40, writes lxc directly (hT is dead).
__global__ void k_bnxc(const float* __restrict__ yT, const float* __restrict__ bnst,
                       const float* __restrict__ gamma_l, const float* __restrict__ beta_l,
                       const float* __restrict__ x, float* __restrict__ lxc) {
    int i = blockIdx.x * 256 + threadIdx.x;  // i = f*NN + n, f in [0,40)
    if (i >= 40 * NN) return;
    int f = i / NN, n = i - f * NN;
    int f2 = f + 40;
    float mu1 = bnst[f] * (1.f / NN);
    float ms1 = bnst[80 + f] * (1.f / NN);
    float v1 = (yT[(size_t)f * NN + n] - mu1) *
               (1.f / sqrtf(fmaxf(ms1 - mu1 * mu1, 0.f) + 1e-5f)) * gamma_l[f] + beta_l[f];
    v1 = fmaxf(v1, 0.f);
    float mu2 = bnst[f2] * (1.f / NN);
    float ms2 = bnst[80 + f2] * (1.f / NN);
    float v2 = (yT[(size_t)f2 * NN + n] - mu2) *
               (1.f / sqrtf(fmaxf(ms2 - mu2 * mu2, 0.f) + 1e-5f)) * gamma_l[f2] + beta_l[f2];
    v2 = fmaxf(v2, 0.f);
    lxc[(size_t)n * 40 + f] = logf(v1 * x[2 * n + 1] + v2 + 1e-6f);
}

// ---------------- tail kernels ----------------
__global__ void k_logagg(const float* __restrict__ lxc, const int* __restrict__ offs,
                         const int* __restrict__ csr, const int* __restrict__ batch,
                         float* __restrict__ pooled) {
    int n = blockIdx.x;
    int tid = threadIdx.x;  // 64
    if (tid >= 40) return;
    int e0 = offs[n], e1 = offs[n + 1];
    float s = 0.f;
    for (int k = e0; k < e1; ++k) s += lxc[(size_t)csr[k] * 40 + tid];
    float v = expf(s + lxc[(size_t)n * 40 + tid]);
    atomicAdd(&pooled[batch[n] * 40 + tid], v);
}

__global__ void k_final(const float* __restrict__ pooled, const int* __restrict__ gcnt,
                        const float* __restrict__ mlW, const float* __restrict__ mlb,
                        const float* __restrict__ m1W, const float* __restrict__ m1b,
                        const float* __restrict__ m2W, const float* __restrict__ m2b,
                        float* __restrict__ out) {
    int g = threadIdx.x;
    if (g >= NG) return;
    float inv = 1.f / fmaxf((float)gcnt[g], 1.f);
    float pl[40];
#pragma unroll
    for (int j = 0; j < 40; j++) pl[j] = pooled[g * 40 + j] * inv;
    float xl = mlb[0];
#pragma unroll
    for (int j = 0; j < 40; j++) xl += pl[j] * mlW[j];
    float acc = m2b[0];
    for (int k = 0; k < 20; k++) {
        float v = m1b[k];
#pragma unroll
        for (int j = 0; j < 40; j++) v += pl[j] * m1W[j * 20 + k];
        v = 20.f - fmaxf(v, 0.f);
        acc += v * m2W[k];
    }
    out[g] = acc + xl;
}

// ---------------- launcher ----------------
extern "C" void kernel_launch(void* const* d_in, const int* in_sizes, int n_in,
                              void* d_out, int out_size, void* d_ws, size_t ws_size,
                              hipStream_t stream) {
    const float* x     = (const float*)d_in[0];
    const int*   ei    = (const int*)d_in[1];
    const int*   batch = (const int*)d_in[2];
    const float* plW   = (const float*)d_in[3];
    const float* plb   = (const float*)d_in[4];
    const float* preW  = (const float*)d_in[5];
    const float* preb  = (const float*)d_in[6];
    const float* postW = (const float*)d_in[7];
    const float* postb = (const float*)d_in[8];
    const float* linW  = (const float*)d_in[9];
    const float* linb  = (const float*)d_in[10];
    const float* bnG   = (const float*)d_in[11];
    const float* bnB   = (const float*)d_in[12];
    const float* mlW   = (const float*)d_in[13];
    const float* mlb   = (const float*)d_in[14];
    const float* m1W   = (const float*)d_in[15];
    const float* m1b   = (const float*)d_in[16];
    const float* m2W   = (const float*)d_in[17];
    const float* m2b   = (const float*)d_in[18];
    float* out = (float*)d_out;
    const int* srcp = ei;
    const int* dstp = ei + NE;

    char* p = (char*)d_ws;
    int*   deg    = (int*)(p + 0);          // 40000 B (zeroed)
    int*   cursor = (int*)(p + 40000);      // 40000 B (zeroed)
    int*   gcnt   = (int*)(p + 80000);      // 256 B   (zeroed)
    float* ald    = (float*)(p + 80256);    // 16 B    (zeroed)
    float* pooled = (float*)(p + 80272);    // 10240 B (zeroed)
    float* bnst   = (float*)(p + 90512);    // 2560 B  (zeroed; atomic-accumulated)
    int*   offs   = (int*)(p + 93072);      // 40016 B
    int*   csr    = (int*)(p + 133088);     // 640000 B
    float* hT     = (float*)(p + 773088);   // 3.2 MB  [80][NN]      (live across layers)
    float* A      = (float*)(p + 3973088);  // 16 MB   [NN][400]
    float* Bt     = (float*)(p + 19973088); // 16 MB   [5][NN][80]
    float* aggT   = (float*)(p + 35973088); // 64 MB   [5*320][NN]
    // Time-disjoint overlays inside the Bt region (Bt dead after k_agg_t):
    float* y0T = (float*)(p + 23173088);    // 3.2 MB  [80][NN]  (k_post atomic -> k_lin)
    float* yT  = (float*)(p + 26373088);    // 3.2 MB  [80][NN]  (k_lin -> bn)
    float* lxc = (float*)(p + 35973088);    // 1.6 MB  [NN][40]  (tail, overlays aggT)

    hipMemsetAsync(d_ws, 0, 93072, stream);
    k_cnt2<<<dim3((NE + 255) / 256), 256, 0, stream>>>(dstp, batch, deg, gcnt);
    k_scan<<<1, 256, 0, stream>>>(deg, offs);
    k_ald<<<dim3((NN + 255) / 256), 256, 0, stream>>>(deg, ald);
    k_fill<<<dim3((NE + 255) / 256), 256, 0, stream>>>(srcp, dstp, offs, cursor, csr);
    k_op0<<<dim3((FEAT * NN + 255) / 256), 256, 0, stream>>>(x, plW, plb, hT);

    for (int l = 0; l < NL; ++l) {
        const float* preW_l  = preW  + (size_t)l * NT * 160 * 80;
        const float* preb_l  = preb  + l * NT * 80;
        const float* postW_l = postW + (size_t)l * NT * 1040 * 16;
        const float* postb_l = postb + l * NT * 16;
        const float* linW_l  = linW  + l * 80 * 80;
        const float* linb_l  = linb  + l * 80;
        float* bnst_l = bnst + l * 160;
        k_mm_ab<<<dim3(625, 2), 256, 0, stream>>>(hT, preW_l, A, Bt);
        k_agg_t<<<dim3(625, 5), 256, 0, stream>>>(A, Bt, offs, csr, preb_l, aggT);
        // y0T overlays Bt[t=1]; zero only after k_agg_t is done reading Bt
        hipMemsetAsync(y0T, 0, (size_t)80 * NN * 4, stream);
        k_post<<<dim3(40, 5, 4), 256, 0, stream>>>(hT, aggT, postW_l, postb_l, offs, ald, y0T);
        k_lin<<<dim3(40, 10), 256, 0, stream>>>(y0T, linW_l, linb_l, yT);
        k_bnstats<<<dim3(80, 8), 256, 0, stream>>>(yT, bnst_l);
        if (l < NL - 1) {
            k_bn<<<dim3((FEAT * NN + 255) / 256), 256, 0, stream>>>(
                yT, bnst_l, bnG + l * 80, bnB + l * 80, hT);
        } else {
            k_bnxc<<<dim3((40 * NN + 255) / 256), 256, 0, stream>>>(
                yT, bnst_l, bnG + l * 80, bnB + l * 80, x, lxc);
        }
    }

    k_logagg<<<dim3(NN), 64, 0, stream>>>(lxc, offs, csr, batch, pooled);
    k_final<<<1, 64, 0, stream>>>(pooled, gcnt, mlW, mlb, m1W, m1b, m2W, m2b, out);
}